// Round 8
// baseline (1289.158 us; speedup 1.0000x reference)
//
#include <hip/hip_runtime.h>
#include <stdint.h>

// Problem constants (from reference): T=128, K=8, H=2048, E=64, I=768
constexpr int Tn = 128;
constexpr int Kn = 8;
constexpr int Hn = 2048;
constexpr int En = 64;
constexpr int In = 768;
constexpr int NP = Tn * Kn;      // 1024 pairs
constexpr int NTI = In / 128;    // 6 col tiles of 128
constexpr int DS = 8;            // d-slabs in gateup
constexpr int DSL = Hn / DS;     // 256 d per slab (64 per wave)

// ---------------- routing: build CSR of pair-ids per expert ----------------
__global__ void route_kernel(const int* __restrict__ idx32,
                             int* __restrict__ offsets,   // E+1 ints (512 B slot)
                             int* __restrict__ entries) { // NP pair ids
  __shared__ int s_cnt[En];
  __shared__ int s_cur[En];
  __shared__ int s_odd_or;
  const int tid = threadIdx.x;
  if (tid == 0) s_odd_or = 0;
  if (tid < En) s_cnt[tid] = 0;
  __syncthreads();
  if (tid < NP / 2) {
    if (idx32[2 * tid + 1] != 0) atomicOr(&s_odd_or, 1);
  }
  __syncthreads();
  const bool is64 = (s_odd_or == 0);
  const int e = is64 ? idx32[2 * tid] : idx32[tid];
  atomicAdd(&s_cnt[e], 1);
  __syncthreads();
  if (tid == 0) {
    int acc = 0;
    for (int i = 0; i < En; ++i) { s_cur[i] = acc; offsets[i] = acc; acc += s_cnt[i]; }
    offsets[En] = acc;
  }
  __syncthreads();
  const int pos = atomicAdd(&s_cur[e], 1);
  entries[pos] = tid;  // pair id = t*K + k
}

// ------------- gateup streaming body: NRB rows, barrier-free hot loop ------
template <int NRB>
__device__ void gus_body(const float* __restrict__ wp,
                         const float (*__restrict__ s_h)[257],
                         float2* __restrict__ red,
                         int wv, int lane, int cntc,
                         float* __restrict__ gup, size_t ap0) {
  float2 acc[NRB];
#pragma unroll
  for (int r = 0; r < NRB; ++r) acc[r] = make_float2(0.f, 0.f);
  const int dl0 = wv * 64;

  // 64 d-rows, straight-line: 8 groups x (8 independent float2 loads + FMAs)
#pragma unroll
  for (int g = 0; g < 8; ++g) {
    float2 wv8[8];
#pragma unroll
    for (int q = 0; q < 8; ++q)
      wv8[q] = *reinterpret_cast<const float2*>(wp + (size_t)(g * 8 + q) * In);
#pragma unroll
    for (int r = 0; r < NRB; ++r) {
      const float4 hA = *reinterpret_cast<const float4*>(&s_h[r][dl0 + g * 8]);
      const float4 hB = *reinterpret_cast<const float4*>(&s_h[r][dl0 + g * 8 + 4]);
      acc[r].x = fmaf(hA.x, wv8[0].x, acc[r].x); acc[r].y = fmaf(hA.x, wv8[0].y, acc[r].y);
      acc[r].x = fmaf(hA.y, wv8[1].x, acc[r].x); acc[r].y = fmaf(hA.y, wv8[1].y, acc[r].y);
      acc[r].x = fmaf(hA.z, wv8[2].x, acc[r].x); acc[r].y = fmaf(hA.z, wv8[2].y, acc[r].y);
      acc[r].x = fmaf(hA.w, wv8[3].x, acc[r].x); acc[r].y = fmaf(hA.w, wv8[3].y, acc[r].y);
      acc[r].x = fmaf(hB.x, wv8[4].x, acc[r].x); acc[r].y = fmaf(hB.x, wv8[4].y, acc[r].y);
      acc[r].x = fmaf(hB.y, wv8[5].x, acc[r].x); acc[r].y = fmaf(hB.y, wv8[5].y, acc[r].y);
      acc[r].x = fmaf(hB.z, wv8[6].x, acc[r].x); acc[r].y = fmaf(hB.z, wv8[6].y, acc[r].y);
      acc[r].x = fmaf(hB.w, wv8[7].x, acc[r].x); acc[r].y = fmaf(hB.w, wv8[7].y, acc[r].y);
    }
  }

  // cross-wave tree reduce (overlays s_h; all barriers are epilogue-only)
  __syncthreads();                 // everyone done reading s_h
  if (wv >= 2) {
#pragma unroll
    for (int r = 0; r < NRB; ++r) red[(r * 2 + (wv - 2)) * 64 + lane] = acc[r];
  }
  __syncthreads();
  if (wv < 2) {
#pragma unroll
    for (int r = 0; r < NRB; ++r) {
      const float2 o = red[(r * 2 + wv) * 64 + lane];
      acc[r].x += o.x; acc[r].y += o.y;
    }
  }
  __syncthreads();
  if (wv == 1) {
#pragma unroll
    for (int r = 0; r < NRB; ++r) red[r * 64 + lane] = acc[r];
  }
  __syncthreads();
  if (wv == 0) {
#pragma unroll
    for (int r = 0; r < NRB; ++r) {
      const float2 o = red[r * 64 + lane];
      const float vx = acc[r].x + o.x;
      const float vy = acc[r].y + o.y;
      if (r < cntc) {
        atomicAdd(&gup[ap0 + (size_t)r * In], vx);
        atomicAdd(&gup[ap0 + (size_t)r * In + 1], vy);
      }
    }
  }
}

// ------------- phase A: barrier-free weight streaming, split-D atomics -----
// grid = 2 * E * NTI * DS; block 256 = 4 waves, each wave owns 64 d.
// gu layout [2][NP][In] fp32 (CSR-position-indexed), zeroed before launch.
__global__ __launch_bounds__(256, 4) void gateup_stream(
    const float* __restrict__ hs, const float* __restrict__ wg,
    const float* __restrict__ wu, const int* __restrict__ offsets,
    const int* __restrict__ entries, float* __restrict__ gu) {
  const int b = blockIdx.x;
  const int ds = b & 7;                 // DS=8
  const int tile = (b >> 3) % NTI;
  const int em = (b >> 3) / NTI;        // e + 64*m
  const int e = em & 63;
  const int m = em >> 6;
  const int beg = offsets[e];
  const int cnt = offsets[e + 1] - beg;
  if (cnt == 0) return;

  const int t = threadIdx.x;
  const int wv = t >> 6;
  const int lane = t & 63;
  const int dbeg = ds * DSL;
  const int col = tile * 128 + lane * 2;

  __shared__ float s_h[32][257];        // +1-pad: 2-way-free stage/epilogue
  __shared__ int s_tok[32];
  float2* red = reinterpret_cast<float2*>(&s_h[0][0]);  // 4096 float2 capacity

  const float* W = m ? wu : wg;
  const float* wp = W + ((size_t)e * Hn + dbeg + wv * 64) * In + col;
  float* gup = gu + (size_t)m * NP * In;

  for (int chunk = 0; chunk < cnt; chunk += 32) {
    const int cntc = min(cnt - chunk, 32);
    const int NRB_rt = (cntc + 7) & ~7;

    __syncthreads();                    // prev epilogue done with red/s_h
    if (t < 32) s_tok[t] = entries[beg + chunk + min(t, cntc - 1)] >> 3;
    __syncthreads();
    {  // stage h rows: r = t&31 (bank-spread), c0 = (t>>5)*32
      const int r = t & 31, c0 = (t >> 5) * 32;
      if (r < NRB_rt) {
        const float* src = hs + (size_t)s_tok[r] * Hn + dbeg + c0;
#pragma unroll
        for (int q = 0; q < 8; ++q)
          *reinterpret_cast<float4*>(&s_h[r][c0 + q * 4]) =
              *reinterpret_cast<const float4*>(src + q * 4);
      }
    }
    __syncthreads();

    const size_t ap0 = (size_t)(beg + chunk) * In + col;
    switch (NRB_rt >> 3) {
      case 1: gus_body<8>(wp, s_h, red, wv, lane, cntc, gup, ap0); break;
      case 2: gus_body<16>(wp, s_h, red, wv, lane, cntc, gup, ap0); break;
      case 3: gus_body<24>(wp, s_h, red, wv, lane, cntc, gup, ap0); break;
      default: gus_body<32>(wp, s_h, red, wv, lane, cntc, gup, ap0); break;
    }
  }
}

// ------------- silu combine: act = silu(gate)*up, in place over gate -------
__global__ void silu_kernel(float* __restrict__ gu) {
  const int i = blockIdx.x * blockDim.x + threadIdx.x;  // over NP*In/4 float4
  float4* g4 = reinterpret_cast<float4*>(gu);
  const float4* u4 = reinterpret_cast<const float4*>(gu + (size_t)NP * In);
  float4 g = g4[i];
  const float4 u = u4[i];
  g.x = g.x / (1.f + __expf(-g.x)) * u.x;
  g.y = g.y / (1.f + __expf(-g.y)) * u.y;
  g.z = g.z / (1.f + __expf(-g.z)) * u.z;
  g.w = g.w / (1.f + __expf(-g.w)) * u.w;
  g4[i] = g;
}

// ---------------- phase B: out[t] += w * act @ Wd (unchanged) --------------
__global__ __launch_bounds__(256, 2) void down_kernel(
    const float* __restrict__ act, const float* __restrict__ wd,
    const float* __restrict__ tkw, const int* __restrict__ offsets,
    const int* __restrict__ entries, float* __restrict__ out) {
  const int e = blockIdx.x >> 4;     // H/128 = 16 tiles
  const int tile = blockIdx.x & 15;
  const int beg = offsets[e];
  const int cnt = offsets[e + 1] - beg;
  if (cnt == 0) return;

  const int wave = threadIdx.x >> 6;
  const int lane = threadIdx.x & 63;
  const int col = tile * 128 + lane * 2;

  __shared__ float s_a[32][64];
  __shared__ int s_tok[32];
  __shared__ int s_arow[32];
  __shared__ float s_w[32];

  const float* wdp = wd + (size_t)e * In * Hn + col;

  for (int chunk = 0; chunk < cnt; chunk += 32) {
    __syncthreads();
    if (threadIdx.x < 32) {
      const int r = threadIdx.x;
      const int rr = min(r, cnt - chunk - 1);
      const int p = entries[beg + chunk + rr];
      s_tok[r] = p >> 3;
      s_w[r] = tkw[p];
      s_arow[r] = beg + chunk + rr;  // CSR position
    }
    __syncthreads();

    float2 acc[8];
#pragma unroll
    for (int j = 0; j < 8; ++j) acc[j] = make_float2(0.f, 0.f);

    for (int i0 = 0; i0 < In; i0 += 64) {
      {
        const int r = threadIdx.x >> 3;
        const int g = (threadIdx.x & 7) * 8;
        const float* src = act + (size_t)s_arow[r] * In + i0 + g;
        const float4 a = *reinterpret_cast<const float4*>(src);
        const float4 b = *reinterpret_cast<const float4*>(src + 4);
        *reinterpret_cast<float4*>(&s_a[r][g]) = a;
        *reinterpret_cast<float4*>(&s_a[r][g + 4]) = b;
      }
      __syncthreads();
      const float* wdi = wdp + (size_t)i0 * Hn;
#pragma unroll 2
      for (int ig = 0; ig < 64; ig += 4) {
        float2 wdv[4];
#pragma unroll
        for (int q = 0; q < 4; ++q)
          wdv[q] = *reinterpret_cast<const float2*>(wdi + (size_t)(ig + q) * Hn);
#pragma unroll
        for (int j = 0; j < 8; ++j) {
          const float4 av = *reinterpret_cast<const float4*>(&s_a[wave * 8 + j][ig]);
          const float avv[4] = {av.x, av.y, av.z, av.w};
#pragma unroll
          for (int q = 0; q < 4; ++q) {
            acc[j].x = fmaf(avv[q], wdv[q].x, acc[j].x);
            acc[j].y = fmaf(avv[q], wdv[q].y, acc[j].y);
          }
        }
      }
      __syncthreads();
    }

#pragma unroll
    for (int j = 0; j < 8; ++j) {
      const int r = wave * 8 + j;
      if (chunk + r < cnt) {
        const float w = s_w[r];
        float* op = out + (size_t)s_tok[r] * Hn + col;
        atomicAdd(op, w * acc[j].x);
        atomicAdd(op + 1, w * acc[j].y);
      }
    }
  }
}

extern "C" void kernel_launch(void* const* d_in, const int* in_sizes, int n_in,
                              void* d_out, int out_size, void* d_ws, size_t ws_size,
                              hipStream_t stream) {
  const float* hs  = (const float*)d_in[0];
  const int*   idx = (const int*)d_in[1];
  const float* tkw = (const float*)d_in[2];
  const float* wg  = (const float*)d_in[3];
  const float* wu  = (const float*)d_in[4];
  const float* wd  = (const float*)d_in[5];
  float* out = (float*)d_out;

  // Workspace: [0,512) offsets | [512,4608) entries | [8192,..) gu[2][NP][In]
  char* ws = (char*)d_ws;
  int* offsets = (int*)ws;
  int* entries = (int*)(ws + 512);
  float* gu    = (float*)(ws + 8192);
  const size_t gu_bytes = (size_t)2 * NP * In * sizeof(float);

  route_kernel<<<1, NP, 0, stream>>>(idx, offsets, entries);
  hipMemsetAsync(d_out, 0, (size_t)Tn * Hn * sizeof(float), stream);
  hipMemsetAsync(gu, 0, gu_bytes, stream);
  gateup_stream<<<2 * En * NTI * DS, 256, 0, stream>>>(hs, wg, wu, offsets, entries, gu);
  silu_kernel<<<NP * In / 4 / 256, 256, 0, stream>>>(gu);
  down_kernel<<<En * (Hn / 128), 256, 0, stream>>>(gu, wd, tkw, offsets, entries, out);
}

// Round 9
// 510.909 us; speedup vs baseline: 2.5233x; 2.5233x over previous
//
#include <hip/hip_runtime.h>
#include <stdint.h>

// Problem constants (from reference): T=128, K=8, H=2048, E=64, I=768
constexpr int Tn = 128;
constexpr int Kn = 8;
constexpr int Hn = 2048;
constexpr int En = 64;
constexpr int In = 768;
constexpr int NP = Tn * Kn;      // 1024 pairs
constexpr int NTI = In / 128;    // 6 col tiles of 128
constexpr int DS = 4;            // d-slabs in gateup
constexpr int DSL = Hn / DS;     // 512 d per slab

// ---------------- routing: build CSR of pair-ids per expert ----------------
__global__ void route_kernel(const int* __restrict__ idx32,
                             int* __restrict__ offsets,   // E+1 ints (512 B slot)
                             int* __restrict__ entries) { // NP pair ids
  __shared__ int s_cnt[En];
  __shared__ int s_cur[En];
  __shared__ int s_odd_or;
  const int tid = threadIdx.x;
  if (tid == 0) s_odd_or = 0;
  if (tid < En) s_cnt[tid] = 0;
  __syncthreads();
  if (tid < NP / 2) {
    if (idx32[2 * tid + 1] != 0) atomicOr(&s_odd_or, 1);
  }
  __syncthreads();
  const bool is64 = (s_odd_or == 0);
  const int e = is64 ? idx32[2 * tid] : idx32[tid];
  atomicAdd(&s_cnt[e], 1);
  __syncthreads();
  if (tid == 0) {
    int acc = 0;
    for (int i = 0; i < En; ++i) { s_cur[i] = acc; offsets[i] = acc; acc += s_cnt[i]; }
    offsets[En] = acc;
  }
  __syncthreads();
  const int pos = atomicAdd(&s_cur[e], 1);
  entries[pos] = tid;  // pair id = t*K + k
}

// ------------- gateup slab body: RPW rows per wave, down_kernel-style ------
// acc[RPW]x2 <= 32 VGPR (RPW<=8) -> no spills. No breaks in unrolled loops.
template <int RPW>
__device__ __forceinline__ void gu_slab(
    const float* __restrict__ hs, const float* __restrict__ wgp,
    const float* __restrict__ wup, const int* __restrict__ s_tok,
    float (*__restrict__ s_h)[64], int t, int wave, int dbeg,
    int cntc, int basecnt, size_t ap0,
    float* __restrict__ gug, float* __restrict__ guu) {
  float2 accg[RPW], accu[RPW];
#pragma unroll
  for (int j = 0; j < RPW; ++j) {
    accg[j] = make_float2(0.f, 0.f);
    accu[j] = make_float2(0.f, 0.f);
  }

  for (int d0 = dbeg; d0 < dbeg + DSL; d0 += 64) {
    {  // stage h[rows, d0:d0+64] -> LDS (32 rows x 64 floats)
      const int r = t >> 3;
      const int g = (t & 7) * 8;
      const float* src = hs + (size_t)s_tok[r] * Hn + d0 + g;
      const float4 a = *reinterpret_cast<const float4*>(src);
      const float4 b = *reinterpret_cast<const float4*>(src + 4);
      *reinterpret_cast<float4*>(&s_h[r][g]) = a;
      *reinterpret_cast<float4*>(&s_h[r][g + 4]) = b;
    }
    __syncthreads();
    const float* wgd = wgp + (size_t)d0 * In;
    const float* wud = wup + (size_t)d0 * In;
#pragma unroll 2
    for (int dg = 0; dg < 64; dg += 4) {
      float2 wgv[4], wuv[4];
#pragma unroll
      for (int q = 0; q < 4; ++q) {
        wgv[q] = *reinterpret_cast<const float2*>(wgd + (size_t)(dg + q) * In);
        wuv[q] = *reinterpret_cast<const float2*>(wud + (size_t)(dg + q) * In);
      }
#pragma unroll
      for (int j = 0; j < RPW; ++j) {
        const float4 hv = *reinterpret_cast<const float4*>(&s_h[wave * RPW + j][dg]);
        const float hvv[4] = {hv.x, hv.y, hv.z, hv.w};
#pragma unroll
        for (int q = 0; q < 4; ++q) {
          accg[j].x = fmaf(hvv[q], wgv[q].x, accg[j].x);
          accg[j].y = fmaf(hvv[q], wgv[q].y, accg[j].y);
          accu[j].x = fmaf(hvv[q], wuv[q].x, accu[j].x);
          accu[j].y = fmaf(hvv[q], wuv[q].y, accu[j].y);
        }
      }
    }
    __syncthreads();
  }

  // epilogue: atomic combine into gu (proven ~payload-cost in R6)
#pragma unroll
  for (int j = 0; j < RPW; ++j) {
    const int row = wave * RPW + j;
    if (row < cntc) {
      const size_t ap = ap0 + (size_t)row * In;
      atomicAdd(&gug[ap], accg[j].x);
      atomicAdd(&gug[ap + 1], accg[j].y);
      atomicAdd(&guu[ap], accu[j].x);
      atomicAdd(&guu[ap + 1], accu[j].y);
    }
  }
  (void)basecnt;
}

// ------------- phase A: split-D gate+up, atomic combine --------------------
// grid = E * NTI * DS (1536 = 6 blocks/CU); block 256 = 4 waves.
// gu layout [2][NP][In] fp32 (CSR-position-indexed), zeroed before launch.
__global__ __launch_bounds__(256, 2) void gateup_splitd(
    const float* __restrict__ hs, const float* __restrict__ wg,
    const float* __restrict__ wu, const int* __restrict__ offsets,
    const int* __restrict__ entries, float* __restrict__ gu) {
  const int ds = blockIdx.x & (DS - 1);
  const int tile = (blockIdx.x >> 2) % NTI;
  const int e = blockIdx.x / (DS * NTI);
  const int beg = offsets[e];
  const int cnt = offsets[e + 1] - beg;
  if (cnt == 0) return;

  const int t = threadIdx.x;
  const int wave = t >> 6;
  const int lane = t & 63;
  const int dbeg = ds * DSL;
  const int col = tile * 128 + lane * 2;

  __shared__ float s_h[32][64];
  __shared__ int s_tok[32];

  const float* wgp = wg + (size_t)e * Hn * In + col;
  const float* wup = wu + (size_t)e * Hn * In + col;
  float* gug = gu;
  float* guu = gu + (size_t)NP * In;

  for (int chunk = 0; chunk < cnt; chunk += 32) {
    const int cntc = min(cnt - chunk, 32);
    const int rpw = (cntc + 3) >> 2;  // 1..8 rows per wave

    __syncthreads();  // prev epilogue/readers done with s_tok/s_h
    if (t < 32) s_tok[t] = entries[beg + chunk + min(t, cntc - 1)] >> 3;
    __syncthreads();

    const size_t ap0 = (size_t)(beg + chunk) * In + col;
    switch (rpw) {
      case 1: gu_slab<1>(hs, wgp, wup, s_tok, s_h, t, wave, dbeg, cntc, cnt, ap0, gug, guu); break;
      case 2: gu_slab<2>(hs, wgp, wup, s_tok, s_h, t, wave, dbeg, cntc, cnt, ap0, gug, guu); break;
      case 3: gu_slab<3>(hs, wgp, wup, s_tok, s_h, t, wave, dbeg, cntc, cnt, ap0, gug, guu); break;
      case 4: gu_slab<4>(hs, wgp, wup, s_tok, s_h, t, wave, dbeg, cntc, cnt, ap0, gug, guu); break;
      case 5: gu_slab<5>(hs, wgp, wup, s_tok, s_h, t, wave, dbeg, cntc, cnt, ap0, gug, guu); break;
      case 6: gu_slab<6>(hs, wgp, wup, s_tok, s_h, t, wave, dbeg, cntc, cnt, ap0, gug, guu); break;
      case 7: gu_slab<7>(hs, wgp, wup, s_tok, s_h, t, wave, dbeg, cntc, cnt, ap0, gug, guu); break;
      default: gu_slab<8>(hs, wgp, wup, s_tok, s_h, t, wave, dbeg, cntc, cnt, ap0, gug, guu); break;
    }
  }
}

// ------------- silu combine: act = silu(gate)*up, in place over gate -------
__global__ void silu_kernel(float* __restrict__ gu) {
  const int i = blockIdx.x * blockDim.x + threadIdx.x;  // over NP*In/4 float4
  float4* g4 = reinterpret_cast<float4*>(gu);
  const float4* u4 = reinterpret_cast<const float4*>(gu + (size_t)NP * In);
  float4 g = g4[i];
  const float4 u = u4[i];
  g.x = g.x / (1.f + __expf(-g.x)) * u.x;
  g.y = g.y / (1.f + __expf(-g.y)) * u.y;
  g.z = g.z / (1.f + __expf(-g.z)) * u.z;
  g.w = g.w / (1.f + __expf(-g.w)) * u.w;
  g4[i] = g;
}

// ---------------- phase B: out[t] += w * act @ Wd (unchanged) --------------
__global__ __launch_bounds__(256, 2) void down_kernel(
    const float* __restrict__ act, const float* __restrict__ wd,
    const float* __restrict__ tkw, const int* __restrict__ offsets,
    const int* __restrict__ entries, float* __restrict__ out) {
  const int e = blockIdx.x >> 4;     // H/128 = 16 tiles
  const int tile = blockIdx.x & 15;
  const int beg = offsets[e];
  const int cnt = offsets[e + 1] - beg;
  if (cnt == 0) return;

  const int wave = threadIdx.x >> 6;
  const int lane = threadIdx.x & 63;
  const int col = tile * 128 + lane * 2;

  __shared__ float s_a[32][64];
  __shared__ int s_tok[32];
  __shared__ int s_arow[32];
  __shared__ float s_w[32];

  const float* wdp = wd + (size_t)e * In * Hn + col;

  for (int chunk = 0; chunk < cnt; chunk += 32) {
    __syncthreads();
    if (threadIdx.x < 32) {
      const int r = threadIdx.x;
      const int rr = min(r, cnt - chunk - 1);
      const int p = entries[beg + chunk + rr];
      s_tok[r] = p >> 3;
      s_w[r] = tkw[p];
      s_arow[r] = beg + chunk + rr;  // CSR position
    }
    __syncthreads();

    float2 acc[8];
#pragma unroll
    for (int j = 0; j < 8; ++j) acc[j] = make_float2(0.f, 0.f);

    for (int i0 = 0; i0 < In; i0 += 64) {
      {
        const int r = threadIdx.x >> 3;
        const int g = (threadIdx.x & 7) * 8;
        const float* src = act + (size_t)s_arow[r] * In + i0 + g;
        const float4 a = *reinterpret_cast<const float4*>(src);
        const float4 b = *reinterpret_cast<const float4*>(src + 4);
        *reinterpret_cast<float4*>(&s_a[r][g]) = a;
        *reinterpret_cast<float4*>(&s_a[r][g + 4]) = b;
      }
      __syncthreads();
      const float* wdi = wdp + (size_t)i0 * Hn;
#pragma unroll 2
      for (int ig = 0; ig < 64; ig += 4) {
        float2 wdv[4];
#pragma unroll
        for (int q = 0; q < 4; ++q)
          wdv[q] = *reinterpret_cast<const float2*>(wdi + (size_t)(ig + q) * Hn);
#pragma unroll
        for (int j = 0; j < 8; ++j) {
          const float4 av = *reinterpret_cast<const float4*>(&s_a[wave * 8 + j][ig]);
          const float avv[4] = {av.x, av.y, av.z, av.w};
#pragma unroll
          for (int q = 0; q < 4; ++q) {
            acc[j].x = fmaf(avv[q], wdv[q].x, acc[j].x);
            acc[j].y = fmaf(avv[q], wdv[q].y, acc[j].y);
          }
        }
      }
      __syncthreads();
    }

#pragma unroll
    for (int j = 0; j < 8; ++j) {
      const int r = wave * 8 + j;
      if (chunk + r < cnt) {
        const float w = s_w[r];
        float* op = out + (size_t)s_tok[r] * Hn + col;
        atomicAdd(op, w * acc[j].x);
        atomicAdd(op + 1, w * acc[j].y);
      }
    }
  }
}

extern "C" void kernel_launch(void* const* d_in, const int* in_sizes, int n_in,
                              void* d_out, int out_size, void* d_ws, size_t ws_size,
                              hipStream_t stream) {
  const float* hs  = (const float*)d_in[0];
  const int*   idx = (const int*)d_in[1];
  const float* tkw = (const float*)d_in[2];
  const float* wg  = (const float*)d_in[3];
  const float* wu  = (const float*)d_in[4];
  const float* wd  = (const float*)d_in[5];
  float* out = (float*)d_out;

  // Workspace: [0,512) offsets | [512,4608) entries | [8192,..) gu[2][NP][In]
  char* ws = (char*)d_ws;
  int* offsets = (int*)ws;
  int* entries = (int*)(ws + 512);
  float* gu    = (float*)(ws + 8192);
  const size_t gu_bytes = (size_t)2 * NP * In * sizeof(float);

  route_kernel<<<1, NP, 0, stream>>>(idx, offsets, entries);
  hipMemsetAsync(d_out, 0, (size_t)Tn * Hn * sizeof(float), stream);
  hipMemsetAsync(gu, 0, gu_bytes, stream);
  gateup_splitd<<<En * NTI * DS, 256, 0, stream>>>(hs, wg, wu, offsets, entries, gu);
  silu_kernel<<<NP * In / 4 / 256, 256, 0, stream>>>(gu);
  down_kernel<<<En * (Hn / 128), 256, 0, stream>>>(gu, wd, tkw, offsets, entries, out);
}

// Round 10
// 457.331 us; speedup vs baseline: 2.8189x; 1.1172x over previous
//
#include <hip/hip_runtime.h>
#include <stdint.h>

// Problem constants (from reference): T=128, K=8, H=2048, E=64, I=768
constexpr int Tn = 128;
constexpr int Kn = 8;
constexpr int Hn = 2048;
constexpr int En = 64;
constexpr int In = 768;
constexpr int NP = Tn * Kn;      // 1024 pairs
constexpr int NTI = In / 128;    // 6 col tiles of 128 (gateup)
constexpr int DS = 4;            // d-slabs in gateup
constexpr int DSL = Hn / DS;     // 512 d per slab
constexpr int DSB = 2;           // i-slabs in down
constexpr int ISL = In / DSB;    // 384 i per slab

// ---------------- routing: build CSR of pair-ids per expert ----------------
__global__ void route_kernel(const int* __restrict__ idx32,
                             int* __restrict__ offsets,   // E+1 ints (512 B slot)
                             int* __restrict__ entries) { // NP pair ids
  __shared__ int s_cnt[En];
  __shared__ int s_cur[En];
  __shared__ int s_odd_or;
  const int tid = threadIdx.x;
  if (tid == 0) s_odd_or = 0;
  if (tid < En) s_cnt[tid] = 0;
  __syncthreads();
  if (tid < NP / 2) {
    if (idx32[2 * tid + 1] != 0) atomicOr(&s_odd_or, 1);
  }
  __syncthreads();
  const bool is64 = (s_odd_or == 0);
  const int e = is64 ? idx32[2 * tid] : idx32[tid];
  atomicAdd(&s_cnt[e], 1);
  __syncthreads();
  if (tid == 0) {
    int acc = 0;
    for (int i = 0; i < En; ++i) { s_cur[i] = acc; offsets[i] = acc; acc += s_cnt[i]; }
    offsets[En] = acc;
  }
  __syncthreads();
  const int pos = atomicAdd(&s_cur[e], 1);
  entries[pos] = tid;  // pair id = t*K + k
}

// ------------- phase A: down_kernel clone, ONE weight stream per block -----
// grid = 2 * E * NTI * DS = 3072; block 256 = 4 waves, 8 rows/wave (static).
// gu layout [2][NP][In] fp32 (CSR-position-indexed), zeroed before launch.
__global__ __launch_bounds__(256, 2) void gateup_clone(
    const float* __restrict__ hs, const float* __restrict__ wg,
    const float* __restrict__ wu, const int* __restrict__ offsets,
    const int* __restrict__ entries, float* __restrict__ gu) {
  const int b = blockIdx.x;
  const int ds = b & (DS - 1);
  const int tile = (b >> 2) % NTI;
  const int em = (b >> 2) / NTI;
  const int e = em & 63;
  const int m = em >> 6;               // 0 = gate, 1 = up
  const int beg = offsets[e];
  const int cnt = offsets[e + 1] - beg;
  if (cnt == 0) return;

  const int wave = threadIdx.x >> 6;
  const int lane = threadIdx.x & 63;
  const int dbeg = ds * DSL;
  const int col = tile * 128 + lane * 2;

  __shared__ float s_h[32][64];
  __shared__ int s_tok[32];

  const float* W = m ? wu : wg;
  const float* wp = W + (size_t)e * Hn * In + col;
  float* gup = gu + (size_t)m * NP * In;

  for (int chunk = 0; chunk < cnt; chunk += 32) {
    __syncthreads();
    if (threadIdx.x < 32) {
      const int r = threadIdx.x;
      s_tok[r] = entries[beg + chunk + min(r, cnt - chunk - 1)] >> 3;  // clamp
    }
    __syncthreads();

    float2 acc[8];
#pragma unroll
    for (int j = 0; j < 8; ++j) acc[j] = make_float2(0.f, 0.f);

    for (int d0 = dbeg; d0 < dbeg + DSL; d0 += 64) {
      {  // stage h[rows, d0:d0+64] -> LDS (32 rows x 64 floats)
        const int r = threadIdx.x >> 3;
        const int g = (threadIdx.x & 7) * 8;
        const float* src = hs + (size_t)s_tok[r] * Hn + d0 + g;
        const float4 a = *reinterpret_cast<const float4*>(src);
        const float4 b4 = *reinterpret_cast<const float4*>(src + 4);
        *reinterpret_cast<float4*>(&s_h[r][g]) = a;
        *reinterpret_cast<float4*>(&s_h[r][g + 4]) = b4;
      }
      __syncthreads();
      const float* wdd = wp + (size_t)d0 * In;
#pragma unroll 2
      for (int dg = 0; dg < 64; dg += 4) {
        float2 wv[4];
#pragma unroll
        for (int q = 0; q < 4; ++q)
          wv[q] = *reinterpret_cast<const float2*>(wdd + (size_t)(dg + q) * In);
#pragma unroll
        for (int j = 0; j < 8; ++j) {
          const float4 hv = *reinterpret_cast<const float4*>(&s_h[wave * 8 + j][dg]);
          const float hvv[4] = {hv.x, hv.y, hv.z, hv.w};
#pragma unroll
          for (int q = 0; q < 4; ++q) {
            acc[j].x = fmaf(hvv[q], wv[q].x, acc[j].x);
            acc[j].y = fmaf(hvv[q], wv[q].y, acc[j].y);
          }
        }
      }
      __syncthreads();
    }

#pragma unroll
    for (int j = 0; j < 8; ++j) {
      const int r = wave * 8 + j;
      if (chunk + r < cnt) {
        const size_t ap = (size_t)(beg + chunk + r) * In + col;
        atomicAdd(&gup[ap], acc[j].x);
        atomicAdd(&gup[ap + 1], acc[j].y);
      }
    }
  }
}

// ------------- silu combine: act = silu(gate)*up, in place over gate -------
__global__ void silu_kernel(float* __restrict__ gu) {
  const int i = blockIdx.x * blockDim.x + threadIdx.x;  // over NP*In/4 float4
  float4* g4 = reinterpret_cast<float4*>(gu);
  const float4* u4 = reinterpret_cast<const float4*>(gu + (size_t)NP * In);
  float4 g = g4[i];
  const float4 u = u4[i];
  g.x = g.x / (1.f + __expf(-g.x)) * u.x;
  g.y = g.y / (1.f + __expf(-g.y)) * u.y;
  g.z = g.z / (1.f + __expf(-g.z)) * u.z;
  g.w = g.w / (1.f + __expf(-g.w)) * u.w;
  g4[i] = g;
}

// ---------------- phase B: out[t] += w * act @ Wd, i-slab split -----------
// grid = E * (H/128) * DSB = 2048; block 256.
__global__ __launch_bounds__(256, 2) void down_split(
    const float* __restrict__ act, const float* __restrict__ wd,
    const float* __restrict__ tkw, const int* __restrict__ offsets,
    const int* __restrict__ entries, float* __restrict__ out) {
  const int b = blockIdx.x;
  const int isl = b & (DSB - 1);
  const int tile = (b >> 1) & 15;    // H/128 = 16 tiles
  const int e = b >> 5;
  const int beg = offsets[e];
  const int cnt = offsets[e + 1] - beg;
  if (cnt == 0) return;

  const int wave = threadIdx.x >> 6;
  const int lane = threadIdx.x & 63;
  const int col = tile * 128 + lane * 2;
  const int ibeg = isl * ISL;

  __shared__ float s_a[32][64];
  __shared__ int s_tok[32];
  __shared__ int s_arow[32];
  __shared__ float s_w[32];

  const float* wdp = wd + (size_t)e * In * Hn + col;

  for (int chunk = 0; chunk < cnt; chunk += 32) {
    __syncthreads();
    if (threadIdx.x < 32) {
      const int r = threadIdx.x;
      const int rr = min(r, cnt - chunk - 1);
      const int p = entries[beg + chunk + rr];
      s_tok[r] = p >> 3;
      s_w[r] = tkw[p];
      s_arow[r] = beg + chunk + rr;  // CSR position
    }
    __syncthreads();

    float2 acc[8];
#pragma unroll
    for (int j = 0; j < 8; ++j) acc[j] = make_float2(0.f, 0.f);

    for (int i0 = ibeg; i0 < ibeg + ISL; i0 += 64) {
      {
        const int r = threadIdx.x >> 3;
        const int g = (threadIdx.x & 7) * 8;
        const float* src = act + (size_t)s_arow[r] * In + i0 + g;
        const float4 a = *reinterpret_cast<const float4*>(src);
        const float4 b4 = *reinterpret_cast<const float4*>(src + 4);
        *reinterpret_cast<float4*>(&s_a[r][g]) = a;
        *reinterpret_cast<float4*>(&s_a[r][g + 4]) = b4;
      }
      __syncthreads();
      const float* wdi = wdp + (size_t)i0 * Hn;
#pragma unroll 2
      for (int ig = 0; ig < 64; ig += 4) {
        float2 wdv[4];
#pragma unroll
        for (int q = 0; q < 4; ++q)
          wdv[q] = *reinterpret_cast<const float2*>(wdi + (size_t)(ig + q) * Hn);
#pragma unroll
        for (int j = 0; j < 8; ++j) {
          const float4 av = *reinterpret_cast<const float4*>(&s_a[wave * 8 + j][ig]);
          const float avv[4] = {av.x, av.y, av.z, av.w};
#pragma unroll
          for (int q = 0; q < 4; ++q) {
            acc[j].x = fmaf(avv[q], wdv[q].x, acc[j].x);
            acc[j].y = fmaf(avv[q], wdv[q].y, acc[j].y);
          }
        }
      }
      __syncthreads();
    }

#pragma unroll
    for (int j = 0; j < 8; ++j) {
      const int r = wave * 8 + j;
      if (chunk + r < cnt) {
        const float w = s_w[r];
        float* op = out + (size_t)s_tok[r] * Hn + col;
        atomicAdd(op, w * acc[j].x);
        atomicAdd(op + 1, w * acc[j].y);
      }
    }
  }
}

extern "C" void kernel_launch(void* const* d_in, const int* in_sizes, int n_in,
                              void* d_out, int out_size, void* d_ws, size_t ws_size,
                              hipStream_t stream) {
  const float* hs  = (const float*)d_in[0];
  const int*   idx = (const int*)d_in[1];
  const float* tkw = (const float*)d_in[2];
  const float* wg  = (const float*)d_in[3];
  const float* wu  = (const float*)d_in[4];
  const float* wd  = (const float*)d_in[5];
  float* out = (float*)d_out;

  // Workspace: [0,512) offsets | [512,4608) entries | [8192,..) gu[2][NP][In]
  char* ws = (char*)d_ws;
  int* offsets = (int*)ws;
  int* entries = (int*)(ws + 512);
  float* gu    = (float*)(ws + 8192);
  const size_t gu_bytes = (size_t)2 * NP * In * sizeof(float);

  route_kernel<<<1, NP, 0, stream>>>(idx, offsets, entries);
  hipMemsetAsync(d_out, 0, (size_t)Tn * Hn * sizeof(float), stream);
  hipMemsetAsync(gu, 0, gu_bytes, stream);
  gateup_clone<<<2 * En * NTI * DS, 256, 0, stream>>>(hs, wg, wu, offsets, entries, gu);
  silu_kernel<<<NP * In / 4 / 256, 256, 0, stream>>>(gu);
  down_split<<<En * 16 * DSB, 256, 0, stream>>>(gu, wd, tkw, offsets, entries, out);
}

// Round 11
// 425.826 us; speedup vs baseline: 3.0274x; 1.0740x over previous
//
#include <hip/hip_runtime.h>
#include <stdint.h>

// Problem constants (from reference): T=128, K=8, H=2048, E=64, I=768
constexpr int Tn = 128;
constexpr int Kn = 8;
constexpr int Hn = 2048;
constexpr int En = 64;
constexpr int In = 768;
constexpr int NP = Tn * Kn;      // 1024 pairs
constexpr int CT = 3;            // col tiles of 256 (gateup)
constexpr int DS = 4;            // d-slabs in gateup
constexpr int DSL = Hn / DS;     // 512 d per slab

// ---------------- routing: build CSR of pair-ids per expert ----------------
__global__ void route_kernel(const int* __restrict__ idx32,
                             int* __restrict__ offsets,   // E+1 ints (512 B slot)
                             int* __restrict__ entries) { // NP pair ids
  __shared__ int s_cnt[En];
  __shared__ int s_cur[En];
  __shared__ int s_odd_or;
  const int tid = threadIdx.x;
  if (tid == 0) s_odd_or = 0;
  if (tid < En) s_cnt[tid] = 0;
  __syncthreads();
  if (tid < NP / 2) {
    if (idx32[2 * tid + 1] != 0) atomicOr(&s_odd_or, 1);
  }
  __syncthreads();
  const bool is64 = (s_odd_or == 0);
  const int e = is64 ? idx32[2 * tid] : idx32[tid];
  atomicAdd(&s_cnt[e], 1);
  __syncthreads();
  if (tid == 0) {
    int acc = 0;
    for (int i = 0; i < En; ++i) { s_cur[i] = acc; offsets[i] = acc; acc += s_cnt[i]; }
    offsets[En] = acc;
  }
  __syncthreads();
  const int pos = atomicAdd(&s_cur[e], 1);
  entries[pos] = tid;  // pair id = t*K + k
}

// ------------- gateup wide body: float4 weight loads, RPW rows/wave --------
template <int RPW>
__device__ __forceinline__ void guw_body(
    const float* __restrict__ hs, const float* __restrict__ wp,
    const int* __restrict__ s_tok, float (*__restrict__ s_h)[64],
    int t, int wave, int dbeg, int cntc, size_t ap0,
    float* __restrict__ gup) {
  float4 acc[RPW];
#pragma unroll
  for (int j = 0; j < RPW; ++j) acc[j] = make_float4(0.f, 0.f, 0.f, 0.f);

  for (int d0 = dbeg; d0 < dbeg + DSL; d0 += 64) {
    {  // stage h[rows, d0:d0+64] -> LDS (32 rows x 64 floats)
      const int r = t >> 3;
      const int g = (t & 7) * 8;
      const float* src = hs + (size_t)s_tok[r] * Hn + d0 + g;
      const float4 a = *reinterpret_cast<const float4*>(src);
      const float4 b4 = *reinterpret_cast<const float4*>(src + 4);
      *reinterpret_cast<float4*>(&s_h[r][g]) = a;
      *reinterpret_cast<float4*>(&s_h[r][g + 4]) = b4;
    }
    __syncthreads();
    const float* wdd = wp + (size_t)d0 * In;
#pragma unroll 2
    for (int dg = 0; dg < 64; dg += 4) {
      float4 wv[4];
#pragma unroll
      for (int q = 0; q < 4; ++q)
        wv[q] = *reinterpret_cast<const float4*>(wdd + (size_t)(dg + q) * In);
#pragma unroll
      for (int j = 0; j < RPW; ++j) {
        const float4 hv = *reinterpret_cast<const float4*>(&s_h[wave * RPW + j][dg]);
        acc[j].x = fmaf(hv.x, wv[0].x, acc[j].x);
        acc[j].y = fmaf(hv.x, wv[0].y, acc[j].y);
        acc[j].z = fmaf(hv.x, wv[0].z, acc[j].z);
        acc[j].w = fmaf(hv.x, wv[0].w, acc[j].w);
        acc[j].x = fmaf(hv.y, wv[1].x, acc[j].x);
        acc[j].y = fmaf(hv.y, wv[1].y, acc[j].y);
        acc[j].z = fmaf(hv.y, wv[1].z, acc[j].z);
        acc[j].w = fmaf(hv.y, wv[1].w, acc[j].w);
        acc[j].x = fmaf(hv.z, wv[2].x, acc[j].x);
        acc[j].y = fmaf(hv.z, wv[2].y, acc[j].y);
        acc[j].z = fmaf(hv.z, wv[2].z, acc[j].z);
        acc[j].w = fmaf(hv.z, wv[2].w, acc[j].w);
        acc[j].x = fmaf(hv.w, wv[3].x, acc[j].x);
        acc[j].y = fmaf(hv.w, wv[3].y, acc[j].y);
        acc[j].z = fmaf(hv.w, wv[3].z, acc[j].z);
        acc[j].w = fmaf(hv.w, wv[3].w, acc[j].w);
      }
    }
    __syncthreads();
  }

#pragma unroll
  for (int j = 0; j < RPW; ++j) {
    const int row = wave * RPW + j;
    if (row < cntc) {
      const size_t ap = ap0 + (size_t)row * In;
      atomicAdd(&gup[ap], acc[j].x);
      atomicAdd(&gup[ap + 1], acc[j].y);
      atomicAdd(&gup[ap + 2], acc[j].z);
      atomicAdd(&gup[ap + 3], acc[j].w);
    }
  }
}

// ------------- phase A: single weight stream, 256-col tiles, float4 -------
// grid = 2 * E * CT * DS = 1536; block 256 = 4 waves.
// gu layout [2][NP][In] fp32 (CSR-position-indexed), zeroed before launch.
__global__ __launch_bounds__(256, 2) void gateup_wide(
    const float* __restrict__ hs, const float* __restrict__ wg,
    const float* __restrict__ wu, const int* __restrict__ offsets,
    const int* __restrict__ entries, float* __restrict__ gu) {
  const int b = blockIdx.x;
  const int ds = b & (DS - 1);
  const int tile = (b >> 2) % CT;
  const int em = (b >> 2) / CT;        // 0..127
  const int e = em & 63;
  const int m = em >> 6;               // 0 = gate, 1 = up
  const int beg = offsets[e];
  const int cnt = offsets[e + 1] - beg;
  if (cnt == 0) return;

  const int t = threadIdx.x;
  const int wave = t >> 6;
  const int lane = t & 63;
  const int dbeg = ds * DSL;
  const int col = tile * 256 + lane * 4;

  __shared__ float s_h[32][64];
  __shared__ int s_tok[32];

  const float* W = m ? wu : wg;
  const float* wp = W + (size_t)e * Hn * In + col;
  float* gup = gu + (size_t)m * NP * In;

  for (int chunk = 0; chunk < cnt; chunk += 32) {
    const int cntc = min(cnt - chunk, 32);

    __syncthreads();
    if (t < 32) s_tok[t] = entries[beg + chunk + min(t, cntc - 1)] >> 3;
    __syncthreads();

    const size_t ap0 = (size_t)(beg + chunk) * In + col;
    if (cntc <= 16)
      guw_body<4>(hs, wp, s_tok, s_h, t, wave, dbeg, cntc, ap0, gup);
    else
      guw_body<8>(hs, wp, s_tok, s_h, t, wave, dbeg, cntc, ap0, gup);
  }
}

// ------------- silu combine: act = silu(gate)*up, in place over gate -------
__global__ void silu_kernel(float* __restrict__ gu) {
  const int i = blockIdx.x * blockDim.x + threadIdx.x;  // over NP*In/4 float4
  float4* g4 = reinterpret_cast<float4*>(gu);
  const float4* u4 = reinterpret_cast<const float4*>(gu + (size_t)NP * In);
  float4 g = g4[i];
  const float4 u = u4[i];
  g.x = g.x / (1.f + __expf(-g.x)) * u.x;
  g.y = g.y / (1.f + __expf(-g.y)) * u.y;
  g.z = g.z / (1.f + __expf(-g.z)) * u.z;
  g.w = g.w / (1.f + __expf(-g.w)) * u.w;
  g4[i] = g;
}

// ---------------- phase B: out[t] += w * act @ Wd (proven R5 form) ---------
// grid = E * (H/128) = 1024; block 256.
__global__ __launch_bounds__(256, 2) void down_kernel(
    const float* __restrict__ act, const float* __restrict__ wd,
    const float* __restrict__ tkw, const int* __restrict__ offsets,
    const int* __restrict__ entries, float* __restrict__ out) {
  const int e = blockIdx.x >> 4;     // H/128 = 16 tiles
  const int tile = blockIdx.x & 15;
  const int beg = offsets[e];
  const int cnt = offsets[e + 1] - beg;
  if (cnt == 0) return;

  const int wave = threadIdx.x >> 6;
  const int lane = threadIdx.x & 63;
  const int col = tile * 128 + lane * 2;

  __shared__ float s_a[32][64];
  __shared__ int s_tok[32];
  __shared__ int s_arow[32];
  __shared__ float s_w[32];

  const float* wdp = wd + (size_t)e * In * Hn + col;

  for (int chunk = 0; chunk < cnt; chunk += 32) {
    __syncthreads();
    if (threadIdx.x < 32) {
      const int r = threadIdx.x;
      const int rr = min(r, cnt - chunk - 1);
      const int p = entries[beg + chunk + rr];
      s_tok[r] = p >> 3;
      s_w[r] = tkw[p];
      s_arow[r] = beg + chunk + rr;  // CSR position
    }
    __syncthreads();

    float2 acc[8];
#pragma unroll
    for (int j = 0; j < 8; ++j) acc[j] = make_float2(0.f, 0.f);

    for (int i0 = 0; i0 < In; i0 += 64) {
      {
        const int r = threadIdx.x >> 3;
        const int g = (threadIdx.x & 7) * 8;
        const float* src = act + (size_t)s_arow[r] * In + i0 + g;
        const float4 a = *reinterpret_cast<const float4*>(src);
        const float4 b4 = *reinterpret_cast<const float4*>(src + 4);
        *reinterpret_cast<float4*>(&s_a[r][g]) = a;
        *reinterpret_cast<float4*>(&s_a[r][g + 4]) = b4;
      }
      __syncthreads();
      const float* wdi = wdp + (size_t)i0 * Hn;
#pragma unroll 2
      for (int ig = 0; ig < 64; ig += 4) {
        float2 wdv[4];
#pragma unroll
        for (int q = 0; q < 4; ++q)
          wdv[q] = *reinterpret_cast<const float2*>(wdi + (size_t)(ig + q) * Hn);
#pragma unroll
        for (int j = 0; j < 8; ++j) {
          const float4 av = *reinterpret_cast<const float4*>(&s_a[wave * 8 + j][ig]);
          const float avv[4] = {av.x, av.y, av.z, av.w};
#pragma unroll
          for (int q = 0; q < 4; ++q) {
            acc[j].x = fmaf(avv[q], wdv[q].x, acc[j].x);
            acc[j].y = fmaf(avv[q], wdv[q].y, acc[j].y);
          }
        }
      }
      __syncthreads();
    }

#pragma unroll
    for (int j = 0; j < 8; ++j) {
      const int r = wave * 8 + j;
      if (chunk + r < cnt) {
        const float w = s_w[r];
        float* op = out + (size_t)s_tok[r] * Hn + col;
        atomicAdd(op, w * acc[j].x);
        atomicAdd(op + 1, w * acc[j].y);
      }
    }
  }
}

extern "C" void kernel_launch(void* const* d_in, const int* in_sizes, int n_in,
                              void* d_out, int out_size, void* d_ws, size_t ws_size,
                              hipStream_t stream) {
  const float* hs  = (const float*)d_in[0];
  const int*   idx = (const int*)d_in[1];
  const float* tkw = (const float*)d_in[2];
  const float* wg  = (const float*)d_in[3];
  const float* wu  = (const float*)d_in[4];
  const float* wd  = (const float*)d_in[5];
  float* out = (float*)d_out;

  // Workspace: [0,512) offsets | [512,4608) entries | [8192,..) gu[2][NP][In]
  char* ws = (char*)d_ws;
  int* offsets = (int*)ws;
  int* entries = (int*)(ws + 512);
  float* gu    = (float*)(ws + 8192);
  const size_t gu_bytes = (size_t)2 * NP * In * sizeof(float);

  route_kernel<<<1, NP, 0, stream>>>(idx, offsets, entries);
  hipMemsetAsync(d_out, 0, (size_t)Tn * Hn * sizeof(float), stream);
  hipMemsetAsync(gu, 0, gu_bytes, stream);
  gateup_wide<<<2 * En * CT * DS, 256, 0, stream>>>(hs, wg, wu, offsets, entries, gu);
  silu_kernel<<<NP * In / 4 / 256, 256, 0, stream>>>(gu);
  down_kernel<<<En * (Hn / 128), 256, 0, stream>>>(gu, wd, tkw, offsets, entries, out);
}